// Round 1
// baseline (293.775 us; speedup 1.0000x reference)
//
#include <hip/hip_runtime.h>
#include <hip/hip_bf16.h>

#define N_ENT 40000
#define NB 64
#define BODY_LEN 3
#define N_REL 48
#define NUM_POS 24
#define THR 1e-20f

// mem layout: entity-major, mem[ent*64 + b]

__global__ void k_vals(const int* __restrict__ qh, const int* __restrict__ qr,
                       const int* __restrict__ tt, const int* __restrict__ eh,
                       const int* __restrict__ et, const int* __restrict__ er,
                       const float* __restrict__ ev, float* __restrict__ vals, int nE) {
    __shared__ long long s_key[NB];
    int tid = threadIdx.x;
    if (tid < NB) {
        s_key[tid] = ((long long)qh[tid] << 32) | ((long long)tt[tid] << 8) | (long long)qr[tid];
    }
    __syncthreads();
    int i = blockIdx.x * blockDim.x + tid;
    if (i < nE) {
        long long k = ((long long)eh[i] << 32) | ((long long)et[i] << 8) | (long long)er[i];
        bool killed = false;
#pragma unroll
        for (int b = 0; b < NB; ++b) killed |= (s_key[b] == k);
        vals[i] = killed ? 0.0f : ev[i];
    }
}

__global__ void k_init(const int* __restrict__ qh, float* __restrict__ mem) {
    int i = blockIdx.x * blockDim.x + threadIdx.x;
    if (i < NB * N_ENT) {
        int b = i & 63;
        int ent = i >> 6;
        mem[i] = (qh[b] == ent) ? 1.0f : 0.0f;
    }
}

// nxt[ent*64+b] = old[ent*64+b] * attention[b, step, 47]
__global__ void k_decay(const float* __restrict__ oldm, float* __restrict__ nxt,
                        const float* __restrict__ attn, int step) {
    __shared__ float s_d[NB];
    if (threadIdx.x < NB)
        s_d[threadIdx.x] = attn[threadIdx.x * (BODY_LEN * N_REL) + step * N_REL + (N_REL - 1)];
    __syncthreads();
    int i = blockIdx.x * 256 + threadIdx.x;
    nxt[i] = oldm[i] * s_d[i & 63];
}

// one wave per edge (grid-stride over waves); lane = batch index
__global__ __launch_bounds__(256) void k_step(
    const int* __restrict__ eh, const int* __restrict__ et, const int* __restrict__ er,
    const float* __restrict__ vals, const float* __restrict__ attn, int step,
    const float* __restrict__ oldm, float* __restrict__ nxt, int nE) {
    __shared__ float s_attn[NB][N_REL + 1];  // stride 49: conflict-free
    int tid = threadIdx.x;
    for (int idx = tid; idx < NB * N_REL; idx += 256) {
        int b = idx / N_REL, r = idx % N_REL;
        s_attn[b][r] = attn[b * (BODY_LEN * N_REL) + step * N_REL + r];
    }
    __syncthreads();
    int lane = tid & 63;
    int wave = (blockIdx.x * 256 + tid) >> 6;
    int nW = (gridDim.x * 256) >> 6;
    for (int e = wave; e < nE; e += nW) {
        float v = vals[e];
        if (v == 0.0f) continue;
        int h = eh[e], t = et[e], r = er[e];
        float mh = oldm[(size_t)h * 64 + lane];
        float mt = oldm[(size_t)t * 64 + lane];
        float c1 = mh * v * s_attn[lane][r];          // fwd: head -> tail
        float c2 = mt * v * s_attn[lane][r + NUM_POS]; // rev: tail -> head
        if (c1 != 0.0f) atomicAdd(&nxt[(size_t)t * 64 + lane], c1);
        if (c2 != 0.0f) atomicAdd(&nxt[(size_t)h * 64 + lane], c2);
    }
}

__global__ void k_sums(const float* __restrict__ mem, float* __restrict__ sums) {
    int tid0 = blockIdx.x * blockDim.x + threadIdx.x;
    int stride = gridDim.x * blockDim.x;  // multiple of 64 -> b fixed per thread
    float acc = 0.0f;
    for (size_t i = tid0; i < (size_t)NB * N_ENT; i += stride) acc += mem[i];
    atomicAdd(&sums[tid0 & 63], acc);
}

// transpose (ent-major -> batch-major) + normalize; out offset by 1 (loss at out[0])
__global__ void k_norm_tr(const float* __restrict__ mem, const float* __restrict__ sums,
                          float* __restrict__ out) {
    __shared__ float tile[64][65];
    __shared__ float s_inv[64];
    int tid = threadIdx.x;
    int e0 = blockIdx.x * 64;
    if (tid < 64) s_inv[tid] = 1.0f / fmaxf(THR, sums[tid]);
#pragma unroll
    for (int k = 0; k < 16; ++k) {
        int idx = k * 256 + tid;
        int el = idx >> 6, b = idx & 63;
        tile[el][b] = mem[(size_t)(e0 + el) * 64 + b];
    }
    __syncthreads();
#pragma unroll
    for (int k = 0; k < 16; ++k) {
        int idx = k * 256 + tid;
        int el = idx & 63, b = idx >> 6;
        out[1 + (size_t)b * N_ENT + e0 + el] = tile[el][b] * s_inv[b];
    }
}

__global__ void k_loss(const float* __restrict__ mem, const float* __restrict__ sums,
                       const int* __restrict__ tt, float* __restrict__ out) {
    int b = threadIdx.x;
    float p = mem[(size_t)tt[b] * 64 + b] / fmaxf(THR, sums[b]);
    float l = -logf(fmaxf(THR, p));
#pragma unroll
    for (int off = 32; off > 0; off >>= 1) l += __shfl_down(l, off);
    if (b == 0) out[0] = l * (1.0f / 64.0f);
}

extern "C" void kernel_launch(void* const* d_in, const int* in_sizes, int n_in,
                              void* d_out, int out_size, void* d_ws, size_t ws_size,
                              hipStream_t stream) {
    const int*   qh   = (const int*)d_in[0];
    const int*   qr   = (const int*)d_in[1];
    const int*   tt   = (const int*)d_in[2];
    const float* attn = (const float*)d_in[3];
    const int*   eh   = (const int*)d_in[4];
    const int*   et   = (const int*)d_in[5];
    const int*   er   = (const int*)d_in[6];
    const float* ev   = (const float*)d_in[7];
    float* out = (float*)d_out;
    int nE = in_sizes[4];

    const size_t MEM_BYTES = (size_t)NB * N_ENT * sizeof(float);  // 10,240,000
    char* ws = (char*)d_ws;
    float* vals = (float*)ws;                       // 1.2 MB
    float* sums = (float*)(ws + (2u << 20));        // 256 B
    float* memA = (float*)(ws + (4u << 20));        // 10.24 MB (always in ws)
    float* memB;
    size_t needBoth = (size_t)(4u << 20) + 2 * MEM_BYTES;
    if (ws_size >= needBoth)
        memB = (float*)(ws + (4u << 20) + MEM_BYTES);
    else
        memB = out + 1;  // fall back: use output region as scratch buffer

    k_vals<<<(nE + 255) / 256, 256, 0, stream>>>(qh, qr, tt, eh, et, er, ev, vals, nE);

    // mem0 -> memB so that after 3 swaps the final state is in memA (ws-backed)
    k_init<<<(NB * N_ENT + 255) / 256, 256, 0, stream>>>(qh, memB);

    float* cur = memB;
    float* nxt = memA;
    for (int s = 0; s < BODY_LEN; ++s) {
        k_decay<<<(NB * N_ENT) / 256, 256, 0, stream>>>(cur, nxt, attn, s);
        k_step<<<2048, 256, 0, stream>>>(eh, et, er, vals, attn, s, cur, nxt, nE);
        float* tmp = cur; cur = nxt; nxt = tmp;
    }
    // cur == memA (final, ent-major, unnormalized)

    hipMemsetAsync(sums, 0, NB * sizeof(float), stream);
    k_sums<<<128, 256, 0, stream>>>(cur, sums);
    k_norm_tr<<<N_ENT / 64, 256, 0, stream>>>(cur, sums, out);
    k_loss<<<1, 64, 0, stream>>>(cur, sums, tt, out);
}

// Round 2
// 182.976 us; speedup vs baseline: 1.6055x; 1.6055x over previous
//
#include <hip/hip_runtime.h>
#include <hip/hip_bf16.h>

#define N_ENT 40000
#define NB 64
#define BODY_LEN 3
#define N_REL 48
#define NUM_POS 24
#define THR 1e-20f

// mem layout: entity-major, mem[ent*64 + b]

__global__ void k_vals(const int* __restrict__ qh, const int* __restrict__ qr,
                       const int* __restrict__ tt, const int* __restrict__ eh,
                       const int* __restrict__ et, const int* __restrict__ er,
                       const float* __restrict__ ev, float* __restrict__ vals,
                       float* __restrict__ sums, int nE) {
    __shared__ long long s_key[NB];
    int tid = threadIdx.x;
    if (tid < NB) {
        s_key[tid] = ((long long)qh[tid] << 32) | ((long long)tt[tid] << 8) | (long long)qr[tid];
        if (blockIdx.x == 0) sums[tid] = 0.0f;  // fold sums-zeroing in here
    }
    __syncthreads();
    int i = blockIdx.x * blockDim.x + tid;
    if (i < nE) {
        long long k = ((long long)eh[i] << 32) | ((long long)et[i] << 8) | (long long)er[i];
        bool killed = false;
#pragma unroll
        for (int b = 0; b < NB; ++b) killed |= (s_key[b] == k);
        vals[i] = killed ? 0.0f : ev[i];
    }
}

// step 0 fused: nxt = one_hot(qh) * decay0  (write-only, no init kernel needed)
__global__ void k_init_decay(const int* __restrict__ qh, const float* __restrict__ attn,
                             float* __restrict__ nxt) {
    __shared__ float s_d[NB];
    __shared__ int s_q[NB];
    if (threadIdx.x < NB) {
        s_d[threadIdx.x] = attn[threadIdx.x * (BODY_LEN * N_REL) + 0 * N_REL + (N_REL - 1)];
        s_q[threadIdx.x] = qh[threadIdx.x];
    }
    __syncthreads();
    int i4 = blockIdx.x * 256 + threadIdx.x;       // float4 index
    int ent = (i4 * 4) >> 6;
    int b0 = (i4 * 4) & 63;
    float4 w;
    w.x = (s_q[b0 + 0] == ent) ? s_d[b0 + 0] : 0.0f;
    w.y = (s_q[b0 + 1] == ent) ? s_d[b0 + 1] : 0.0f;
    w.z = (s_q[b0 + 2] == ent) ? s_d[b0 + 2] : 0.0f;
    w.w = (s_q[b0 + 3] == ent) ? s_d[b0 + 3] : 0.0f;
    ((float4*)nxt)[i4] = w;
}

// nxt = old * decay; also emits per-entity active bitmap of `old` via ballot
__global__ void k_decay(const float* __restrict__ oldm, float* __restrict__ nxt,
                        const float* __restrict__ attn, int step,
                        unsigned char* __restrict__ active) {
    __shared__ float s_d[NB];
    if (threadIdx.x < NB)
        s_d[threadIdx.x] = attn[threadIdx.x * (BODY_LEN * N_REL) + step * N_REL + (N_REL - 1)];
    __syncthreads();
    int i4 = blockIdx.x * 256 + threadIdx.x;       // float4 index
    float4 v = ((const float4*)oldm)[i4];
    int b0 = (threadIdx.x * 4) & 63;
    float4 w;
    w.x = v.x * s_d[b0 + 0];
    w.y = v.y * s_d[b0 + 1];
    w.z = v.z * s_d[b0 + 2];
    w.w = v.w * s_d[b0 + 3];
    ((float4*)nxt)[i4] = w;
    bool nz = (v.x != 0.0f) | (v.y != 0.0f) | (v.z != 0.0f) | (v.w != 0.0f);
    unsigned long long m = __ballot(nz);
    int lane = threadIdx.x & 63;
    if ((lane & 15) == 0) {                        // lanes 0,16,32,48 own entities 0..3 of wave
        int ent = (i4 * 4) >> 6;
        active[ent] = ((m >> lane) & 0xFFFFULL) ? 1 : 0;
    }
}

// one wave per edge; lane = batch index. STEP0: gather source is analytic one-hot.
template <bool STEP0>
__global__ __launch_bounds__(256) void k_step(
    const int* __restrict__ eh, const int* __restrict__ et, const int* __restrict__ er,
    const float* __restrict__ vals, const float* __restrict__ attn, int step,
    const float* __restrict__ oldm, const unsigned char* __restrict__ active,
    const int* __restrict__ qh, float* __restrict__ nxt, int nE) {
    __shared__ float s_attn[NB][N_REL + 1];  // stride 49: conflict-free
    int tid = threadIdx.x;
    for (int idx = tid; idx < NB * N_REL; idx += 256) {
        int b = idx / N_REL, r = idx % N_REL;
        s_attn[b][r] = attn[b * (BODY_LEN * N_REL) + step * N_REL + r];
    }
    __syncthreads();
    int lane = tid & 63;
    int myqh = STEP0 ? qh[lane] : 0;
    int wave = (blockIdx.x * 256 + tid) >> 6;
    int nW = (gridDim.x * 256) >> 6;

    int e = wave;
    // dual-slot: hoist both edges' meta loads before any branch (2x load MLP)
    for (; e + nW < nE; e += 2 * nW) {
        int e1 = e + nW;
        int h0 = eh[e],  t0 = et[e],  r0 = er[e];  float v0 = vals[e];
        int h1 = eh[e1], t1 = et[e1], r1 = er[e1]; float v1 = vals[e1];
        if (STEP0) {
            bool hh0 = (h0 == myqh), ht0 = (t0 == myqh);
            bool hh1 = (h1 == myqh), ht1 = (t1 == myqh);
            unsigned long long b0m = __ballot(hh0 || ht0);
            unsigned long long b1m = __ballot(hh1 || ht1);
            if (b0m && v0 != 0.0f) {
                float c1 = (hh0 ? v0 : 0.0f) * s_attn[lane][r0];
                float c2 = (ht0 ? v0 : 0.0f) * s_attn[lane][r0 + NUM_POS];
                if (c1 != 0.0f) atomicAdd(&nxt[(size_t)t0 * 64 + lane], c1);
                if (c2 != 0.0f) atomicAdd(&nxt[(size_t)h0 * 64 + lane], c2);
            }
            if (b1m && v1 != 0.0f) {
                float c1 = (hh1 ? v1 : 0.0f) * s_attn[lane][r1];
                float c2 = (ht1 ? v1 : 0.0f) * s_attn[lane][r1 + NUM_POS];
                if (c1 != 0.0f) atomicAdd(&nxt[(size_t)t1 * 64 + lane], c1);
                if (c2 != 0.0f) atomicAdd(&nxt[(size_t)h1 * 64 + lane], c2);
            }
        } else {
            unsigned a0 = (unsigned)active[h0] | (unsigned)active[t0];
            unsigned a1 = (unsigned)active[h1] | (unsigned)active[t1];
            if (a0 && v0 != 0.0f) {
                float mh = oldm[(size_t)h0 * 64 + lane];
                float mt = oldm[(size_t)t0 * 64 + lane];
                float c1 = mh * v0 * s_attn[lane][r0];
                float c2 = mt * v0 * s_attn[lane][r0 + NUM_POS];
                if (c1 != 0.0f) atomicAdd(&nxt[(size_t)t0 * 64 + lane], c1);
                if (c2 != 0.0f) atomicAdd(&nxt[(size_t)h0 * 64 + lane], c2);
            }
            if (a1 && v1 != 0.0f) {
                float mh = oldm[(size_t)h1 * 64 + lane];
                float mt = oldm[(size_t)t1 * 64 + lane];
                float c1 = mh * v1 * s_attn[lane][r1];
                float c2 = mt * v1 * s_attn[lane][r1 + NUM_POS];
                if (c1 != 0.0f) atomicAdd(&nxt[(size_t)t1 * 64 + lane], c1);
                if (c2 != 0.0f) atomicAdd(&nxt[(size_t)h1 * 64 + lane], c2);
            }
        }
    }
    for (; e < nE; e += nW) {
        int h = eh[e], t = et[e], r = er[e];
        float v = vals[e];
        if (STEP0) {
            bool hh = (h == myqh), ht = (t == myqh);
            if (__ballot(hh || ht) == 0ULL || v == 0.0f) continue;
            float c1 = (hh ? v : 0.0f) * s_attn[lane][r];
            float c2 = (ht ? v : 0.0f) * s_attn[lane][r + NUM_POS];
            if (c1 != 0.0f) atomicAdd(&nxt[(size_t)t * 64 + lane], c1);
            if (c2 != 0.0f) atomicAdd(&nxt[(size_t)h * 64 + lane], c2);
        } else {
            if (((unsigned)active[h] | (unsigned)active[t]) == 0 || v == 0.0f) continue;
            float mh = oldm[(size_t)h * 64 + lane];
            float mt = oldm[(size_t)t * 64 + lane];
            float c1 = mh * v * s_attn[lane][r];
            float c2 = mt * v * s_attn[lane][r + NUM_POS];
            if (c1 != 0.0f) atomicAdd(&nxt[(size_t)t * 64 + lane], c1);
            if (c2 != 0.0f) atomicAdd(&nxt[(size_t)h * 64 + lane], c2);
        }
    }
}

__global__ void k_sums(const float* __restrict__ mem, float* __restrict__ sums) {
    __shared__ float s_s[NB];
    if (threadIdx.x < NB) s_s[threadIdx.x] = 0.0f;
    __syncthreads();
    const float4* m4 = (const float4*)mem;
    const int total4 = NB * N_ENT / 4;
    float4 acc = {0.0f, 0.0f, 0.0f, 0.0f};
    for (int i = blockIdx.x * 256 + threadIdx.x; i < total4; i += gridDim.x * 256) {
        float4 v = m4[i];
        acc.x += v.x; acc.y += v.y; acc.z += v.z; acc.w += v.w;
    }
    int b0 = (threadIdx.x * 4) & 63;   // stride is multiple of 16 float4s -> b fixed
    atomicAdd(&s_s[b0 + 0], acc.x);
    atomicAdd(&s_s[b0 + 1], acc.y);
    atomicAdd(&s_s[b0 + 2], acc.z);
    atomicAdd(&s_s[b0 + 3], acc.w);
    __syncthreads();
    if (threadIdx.x < NB) atomicAdd(&sums[threadIdx.x], s_s[threadIdx.x]);
}

// transpose (ent-major -> batch-major) + normalize; block N_ENT/64 computes the loss
__global__ void k_norm_tr(const float* __restrict__ mem, const float* __restrict__ sums,
                          const int* __restrict__ tt, float* __restrict__ out) {
    if (blockIdx.x == N_ENT / 64) {  // loss block
        int b = threadIdx.x;
        if (b < 64) {
            float p = mem[(size_t)tt[b] * 64 + b] / fmaxf(THR, sums[b]);
            float l = -logf(fmaxf(THR, p));
#pragma unroll
            for (int off = 32; off > 0; off >>= 1) l += __shfl_down(l, off);
            if (b == 0) out[0] = l * (1.0f / 64.0f);
        }
        return;
    }
    __shared__ float tile[64][65];
    __shared__ float s_inv[64];
    int tid = threadIdx.x;
    int e0 = blockIdx.x * 64;
    if (tid < 64) s_inv[tid] = 1.0f / fmaxf(THR, sums[tid]);
    const float4* m4 = (const float4*)(mem + (size_t)e0 * 64);
#pragma unroll
    for (int k = 0; k < 4; ++k) {
        int i4 = k * 256 + tid;         // 1024 float4 = 4096 floats
        float4 v = m4[i4];
        int el = i4 >> 4, b0 = (i4 * 4) & 63;
        tile[el][b0 + 0] = v.x; tile[el][b0 + 1] = v.y;
        tile[el][b0 + 2] = v.z; tile[el][b0 + 3] = v.w;
    }
    __syncthreads();
#pragma unroll
    for (int k = 0; k < 16; ++k) {
        int idx = k * 256 + tid;
        int el = idx & 63, b = idx >> 6;
        out[1 + (size_t)b * N_ENT + e0 + el] = tile[el][b] * s_inv[b];
    }
}

extern "C" void kernel_launch(void* const* d_in, const int* in_sizes, int n_in,
                              void* d_out, int out_size, void* d_ws, size_t ws_size,
                              hipStream_t stream) {
    const int*   qh   = (const int*)d_in[0];
    const int*   qr   = (const int*)d_in[1];
    const int*   tt   = (const int*)d_in[2];
    const float* attn = (const float*)d_in[3];
    const int*   eh   = (const int*)d_in[4];
    const int*   et   = (const int*)d_in[5];
    const int*   er   = (const int*)d_in[6];
    const float* ev   = (const float*)d_in[7];
    float* out = (float*)d_out;
    int nE = in_sizes[4];

    const size_t MEM_BYTES = (size_t)NB * N_ENT * sizeof(float);  // 10,240,000
    char* ws = (char*)d_ws;
    float*         vals   = (float*)ws;                    // 1.2 MB
    float*         sums   = (float*)(ws + (2u << 20));     // 256 B
    unsigned char* active = (unsigned char*)(ws + (2u << 20) + 4096);  // 40 KB
    float* memA = (float*)(ws + (4u << 20));               // 10.24 MB (always ws)
    float* memB;
    size_t needBoth = (size_t)(4u << 20) + 2 * MEM_BYTES;
    if (ws_size >= needBoth)
        memB = (float*)(ws + (4u << 20) + MEM_BYTES);
    else
        memB = out + 1;  // fallback scratch; k_norm_tr overwrites it at the end

    const int NE_F4 = NB * N_ENT / 4 / 256;  // 2500 blocks

    k_vals<<<(nE + 255) / 256, 256, 0, stream>>>(qh, qr, tt, eh, et, er, ev, vals, sums, nE);

    // step 0: cur is the virtual one-hot; nxt = memA
    k_init_decay<<<NE_F4, 256, 0, stream>>>(qh, attn, memA);
    k_step<true><<<2048, 256, 0, stream>>>(eh, et, er, vals, attn, 0,
                                           nullptr, nullptr, qh, memA, nE);
    // steps 1,2: ping-pong memA <-> memB; final lands in memA
    float* cur = memA;
    float* nxt = memB;
    for (int s = 1; s < BODY_LEN; ++s) {
        k_decay<<<NE_F4, 256, 0, stream>>>(cur, nxt, attn, s, active);
        k_step<false><<<2048, 256, 0, stream>>>(eh, et, er, vals, attn, s,
                                                cur, active, nullptr, nxt, nE);
        float* tmp = cur; cur = nxt; nxt = tmp;
    }
    // cur == memA (final, ent-major, unnormalized)

    k_sums<<<128, 256, 0, stream>>>(cur, sums);
    k_norm_tr<<<N_ENT / 64 + 1, 256, 0, stream>>>(cur, sums, tt, out);
}